// Round 2
// baseline (125.358 us; speedup 1.0000x reference)
//
#include <hip/hip_runtime.h>
#include <math.h>

#define N_WIRES 8
#define N_LAYERS 6
#define NG 49          // grid per axis (frequencies |n|<=24 -> 49 samples exact)
#define NG2 (NG * NG)  // 2401

// ws layout (bytes):
//   E  : [0, 76832)        8 x 2401 floats (grid EVs, [i][a*49+b])
//   Fb : [76832, +65536)   MFMA-B-fragment-ordered f16 F (pi folded):
//        frag fid=((i*4+ntile)*2+chunk): 64 lanes x 8 f16;
//        lane q*16+n, elem j  =  F_i[k=ntile*16+n][l=chunk*32+q*8+j]
//        (zero for k>=49 or l>=52)
#define WS_E_OFF 0
#define WS_FB_OFF 76832

typedef _Float16 half8 __attribute__((ext_vector_type(8)));
typedef float f32x4 __attribute__((ext_vector_type(4)));

// ---------------------------------------------------------------------------
// Grid circuit eval, block-per-point (round-1 structure: shfl for intra-wave
// wires, ping-pong LDS + 1 barrier for cross-wave exchanges).
// ---------------------------------------------------------------------------
__global__ __launch_bounds__(256) void qnn_grid_lds(const float* __restrict__ w,
                                                    float* __restrict__ E) {
    __shared__ float gates[N_LAYERS * N_WIRES * 8];
    __shared__ float2 bufA[256];
    __shared__ float2 bufB[256];
    __shared__ float partial[4][8];

    const int tid = threadIdx.x;
    const int g = blockIdx.x;
    const int ga = (g * 1338) >> 16;  // g/49, exact for g < 2404
    const int gb = g - ga * NG;
    const float step = (float)(2.0 * M_PI / 49.0);

    if (tid < N_LAYERS * N_WIRES) {
        const int i = tid & 7;
        float wx = w[tid * 3 + 0], wy = w[tid * 3 + 1], wz = w[tid * 3 + 2];
        float sx, cx, sy, cy, sz, cz;
        sincosf(0.5f * wx, &sx, &cx);
        sincosf(0.5f * wy, &sy, &cy);
        sincosf(0.5f * wz, &sz, &cz);
        float A00r = cy * cx, A00i = sy * sx;
        float A01r = -sy * cx, A01i = -cy * sx;
        float A10r = sy * cx, A10i = -cy * sx;
        float A11r = cy * cx, A11i = -sy * sx;
        float U00r = A00r * cz + A00i * sz, U00i = A00i * cz - A00r * sz;
        float U01r = A01r * cz + A01i * sz, U01i = A01i * cz - A01r * sz;
        float U10r = A10r * cz - A10i * sz, U10i = A10i * cz + A10r * sz;
        float U11r = A11r * cz - A11i * sz, U11i = A11i * cz + A11r * sz;
        float V00r, V00i, V01r, V01i, V10r, V10i, V11r, V11i;
        if ((i & 1) == 0) {
            V00r = U01i; V00i = -U01r;
            V01r = U00i; V01i = -U00r;
            V10r = U11i; V10i = -U11r;
            V11r = U10i; V11i = -U10r;
        } else {
            V00r = U01r;  V00i = U01i;
            V01r = -U00r; V01i = -U00i;
            V10r = U11r;  V10i = U11i;
            V11r = -U10r; V11i = -U10i;
        }
        const float xx = (i & 1) ? (step * (float)gb) : (step * (float)ga);
        float se, ce;
        sincosf(0.5f * xx, &se, &ce);
        float* o = gates + tid * 8;
        o[0] = ce * U00r + se * V00r;  o[1] = ce * U00i + se * V00i;
        o[2] = ce * U01r + se * V01r;  o[3] = ce * U01i + se * V01i;
        o[4] = ce * U10r + se * V10r;  o[5] = ce * U10i + se * V10i;
        o[6] = ce * U11r + se * V11r;  o[7] = ce * U11i + se * V11i;
    }

    float ar = (tid == 0) ? 1.0f : 0.0f;
    float ai = 0.0f;
    __syncthreads();

    int flip = 0;
    for (int l = 0; l < N_LAYERS; ++l) {
        #pragma unroll
        for (int i = 0; i < 2; ++i) {
            const float* gm = gates + (l * 8 + i) * 8;
            const int p = 7 - i;
            const int m = 1 << p;
            const int bit = (tid >> p) & 1;
            float2* buf = flip ? bufB : bufA;
            flip ^= 1;
            buf[tid] = make_float2(ar, ai);
            __syncthreads();
            float2 other = buf[tid ^ m];
            float a0r = bit ? other.x : ar, a0i = bit ? other.y : ai;
            float a1r = bit ? ar : other.x, a1i = bit ? ai : other.y;
            float c0r = gm[bit * 4 + 0], c0i = gm[bit * 4 + 1];
            float c1r = gm[bit * 4 + 2], c1i = gm[bit * 4 + 3];
            float nr = c0r * a0r - c0i * a0i + c1r * a1r - c1i * a1i;
            float ni = c0r * a0i + c0i * a0r + c1r * a1i + c1i * a1r;
            ar = nr; ai = ni;
        }
        #pragma unroll
        for (int i = 2; i < 8; ++i) {
            const float* gm = gates + (l * 8 + i) * 8;
            const int p = 7 - i;
            const int m = 1 << p;
            const int bit = (tid >> p) & 1;
            float otr = __shfl_xor(ar, m);
            float oti = __shfl_xor(ai, m);
            float a0r = bit ? otr : ar, a0i = bit ? oti : ai;
            float a1r = bit ? ar : otr, a1i = bit ? ai : oti;
            float c0r = gm[bit * 4 + 0], c0i = gm[bit * 4 + 1];
            float c1r = gm[bit * 4 + 2], c1i = gm[bit * 4 + 3];
            float nr = c0r * a0r - c0i * a0i + c1r * a1r - c1i * a1i;
            float ni = c0r * a0i + c0i * a0r + c1r * a1i + c1i * a1r;
            ar = nr; ai = ni;
        }
        {
            float2* buf = flip ? bufB : bufA;
            flip ^= 1;
            buf[tid] = make_float2(ar, ai);
            __syncthreads();
            float2 src = buf[tid ^ (tid >> 1)];
            ar = src.x; ai = src.y;
        }
    }

    float p = ar * ar + ai * ai;
    float ev[8];
    #pragma unroll
    for (int i = 0; i < 8; ++i) ev[i] = ((tid >> (7 - i)) & 1) ? -p : p;
    #pragma unroll
    for (int i = 0; i < 8; ++i) {
        #pragma unroll
        for (int s = 1; s < 64; s <<= 1) ev[i] += __shfl_xor(ev[i], s);
    }
    const int wave = tid >> 6, lane = tid & 63;
    if (lane == 0) {
        #pragma unroll
        for (int i = 0; i < 8; ++i) partial[wave][i] = ev[i];
    }
    __syncthreads();
    if (tid < 8) {
        E[tid * NG2 + g] = partial[0][tid] + partial[1][tid] + partial[2][tid] + partial[3][tid];
    }
}

// ---------------------------------------------------------------------------
// Fused separable 2D DFT writing MFMA-B-fragment-ordered f16 (round-1
// structure: exact mod-49 sincos table, no serial recurrence).
// ---------------------------------------------------------------------------
__global__ __launch_bounds__(64) void dft2(const float* __restrict__ E,
                                           _Float16* __restrict__ Fb) {
    const int kp = blockIdx.x, i = blockIdx.y, t = threadIdx.x;
    __shared__ float Es[NG2];
    __shared__ float H[NG];
    __shared__ float tc[NG], ts[NG];
    const float step = (float)(2.0 * M_PI / 49.0);
    const float PI = 3.14159265358979323846f;

    if (t < NG) {
        float s, c;
        sincosf(step * (float)t, &s, &c);
        tc[t] = c; ts[t] = s;
    }
    if (kp < NG) {
        for (int e = t; e < NG2; e += 64) Es[e] = E[i * NG2 + e];
    }
    __syncthreads();

    if (kp < NG && t < NG) {
        const int b = t;
        const int n = (kp + 1) >> 1;  // 0 for kp==0
        const bool use_cos = (kp & 1) || (kp == 0);
        float acc = 0.f;
        int j = 0;
        for (int a = 0; a < NG; ++a) {
            acc = fmaf(Es[a * NG + b], use_cos ? tc[j] : ts[j], acc);
            j += n; if (j >= NG) j -= NG;
        }
        acc *= (kp == 0) ? (1.0f / 49.0f) : (2.0f / 49.0f);
        H[b] = acc;
    }
    __syncthreads();

    const int l = t;
    float acc = 0.f;
    if (kp < NG && l < NG) {
        const int n = (l + 1) >> 1;  // 0 for l==0
        const bool use_cos = (l & 1) || (l == 0);
        int j = 0;
        for (int b = 0; b < NG; ++b) {
            acc = fmaf(H[b], use_cos ? tc[j] : ts[j], acc);
            j += n; if (j >= NG) j -= NG;
        }
        acc *= (l == 0) ? (PI / 49.0f) : (2.0f * PI / 49.0f);
    }
    {
        const int ntile = kp >> 4, n = kp & 15;
        const int chunk = l >> 5, lrem = l & 31;
        const int q = lrem >> 3, j = lrem & 7;
        const int fid = (i * 4 + ntile) * 2 + chunk;
        Fb[fid * 512 + (q * 16 + n) * 8 + j] = (_Float16)acc;
    }
}

// ---------------------------------------------------------------------------
// MFMA contraction. NEW this round: B-fragments staged through LDS once per
// block (was: each of 4 waves loaded all frags from global -> 512 MB of L2
// traffic; now: 128 MB). Reg-staged (float4 load -> ds_write_b128), with the
// next i-pair's global loads issued right after the current ds_reads so HBM/
// L2 latency hides under MFMA+epilogue. MFMA inputs/order byte-identical.
// ---------------------------------------------------------------------------
#define V0PAD 68

__global__ __launch_bounds__(256) void contract_mfma(const float* __restrict__ x,
                                                     const _Float16* __restrict__ Fb,
                                                     float* __restrict__ out, int B) {
    __shared__ float xs0[64], xs1[64];
    __shared__ float v0t[64 * V0PAD];          // 17.4 KB
    __shared__ __align__(16) float4 fbS[1024]; // 16 KB fragment staging

    const int tid = threadIdx.x;
    const int bbase = blockIdx.x * 64;
    if (bbase >= B) return;

    if (tid < 64) {
        float2 xv = ((const float2*)x)[bbase + tid];
        xs0[tid] = xv.x;
        xs1[tid] = xv.y;
    }
    __syncthreads();

    // ---- v0 table: thread t -> batch b=t&63, k-segment s=t>>6 (16 k's) ----
    {
        const int b = tid & 63, s = tid >> 6;
        const float x0 = xs0[b];
        float c1, s1;
        sincosf(x0, &s1, &c1);
        float cb, sb;
        sincosf((float)(8 * s) * x0, &sb, &cb);
        float* row = v0t + b * V0PAD + 16 * s;
        const int k0 = 16 * s;
        row[0] = (k0 == 0) ? 1.0f : ((k0 < NG) ? sb : 0.0f);
        float cm = cb, sm = sb;
        #pragma unroll
        for (int j = 1; j < 16; ++j) {
            if (j & 1) {
                float c2 = cm * c1 - sm * s1, s2 = sm * c1 + cm * s1;
                cm = c2; sm = s2;
            }
            float val = (j & 1) ? cm : sm;
            row[j] = ((k0 + j) < NG) ? val : 0.0f;
        }
    }

    const int lane = tid & 63;
    const int w = tid >> 6;
    const int q = lane >> 4;

    // ---- A fragments (built once, reused for all 4 i-pairs) ----
    const float x1v = xs1[w * 16 + (lane & 15)];
    float c1, s1;
    sincosf(x1v, &s1, &c1);
    half8 afrag[2];
    #pragma unroll
    for (int c = 0; c < 2; ++c) {
        const int l0 = c * 32 + q * 8;
        float cb, sb;
        sincosf((float)(l0 >> 1) * x1v, &sb, &cb);
        float vals[8];
        vals[0] = (l0 == 0) ? 1.0f : sb;
        float cm = cb, sm = sb;
        #pragma unroll
        for (int j = 1; j < 8; ++j) {
            if (j & 1) {
                float c2 = cm * c1 - sm * s1, s2 = sm * c1 + cm * s1;
                cm = c2; sm = s2;
            }
            vals[j] = (j & 1) ? cm : sm;
        }
        #pragma unroll
        for (int j = 0; j < 8; ++j) {
            afrag[c][j] = (_Float16)(((l0 + j) < 52) ? vals[j] : 0.0f);
        }
    }

    // ---- prefetch i-pair 0's 16 KB fragment chunk into registers ----
    float4 stg[4];
    {
        const float4* src = (const float4*)Fb;  // 16B-aligned (ws offset 76832)
        #pragma unroll
        for (int j = 0; j < 4; ++j) stg[j] = src[tid + j * 256];
    }

    __syncthreads();  // v0t ready

    const half8* FBl = (const half8*)fbS;

    #pragma unroll 1
    for (int ip = 0; ip < 4; ++ip) {
        const int i0 = ip * 2;

        // stage current chunk regs -> LDS (prev readers done: barrier below)
        #pragma unroll
        for (int j = 0; j < 4; ++j) fbS[tid + j * 256] = stg[j];
        __syncthreads();

        // fragments from LDS (same index order as the old global loads)
        half8 bfrag[16];
        #pragma unroll
        for (int f = 0; f < 16; ++f) bfrag[f] = FBl[f * 64 + lane];

        // issue next chunk's global loads now; latency hides under MFMA+epi
        if (ip < 3) {
            const float4* src = (const float4*)(Fb + (size_t)(ip + 1) * 8192);
            #pragma unroll
            for (int j = 0; j < 4; ++j) stg[j] = src[tid + j * 256];
        }

        f32x4 acc[8];
        #pragma unroll
        for (int t = 0; t < 8; ++t) {
            f32x4 z = {0.f, 0.f, 0.f, 0.f};
            acc[t] = __builtin_amdgcn_mfma_f32_16x16x32_f16(afrag[0], bfrag[t * 2 + 0], z, 0, 0, 0);
            acc[t] = __builtin_amdgcn_mfma_f32_16x16x32_f16(afrag[1], bfrag[t * 2 + 1], acc[t], 0, 0, 0);
        }

        float res[2][4];
        #pragma unroll
        for (int ii = 0; ii < 2; ++ii)
            #pragma unroll
            for (int r = 0; r < 4; ++r) res[ii][r] = 0.f;

        #pragma unroll
        for (int ii = 0; ii < 2; ++ii)
            #pragma unroll
            for (int nt = 0; nt < 4; ++nt) {
                f32x4 a = acc[ii * 4 + nt];
                #pragma unroll
                for (int r = 0; r < 4; ++r) {
                    const int bloc = w * 16 + q * 4 + r;
                    float v0 = v0t[bloc * V0PAD + nt * 16 + (lane & 15)];
                    res[ii][r] = fmaf(a[r], v0, res[ii][r]);
                }
            }

        #pragma unroll
        for (int ii = 0; ii < 2; ++ii)
            #pragma unroll
            for (int r = 0; r < 4; ++r) {
                float v = res[ii][r];
                v += __shfl_xor(v, 1);
                v += __shfl_xor(v, 2);
                v += __shfl_xor(v, 4);
                v += __shfl_xor(v, 8);
                res[ii][r] = v;
            }

        if ((lane & 15) == 0) {
            #pragma unroll
            for (int r = 0; r < 4; ++r) {
                const int b = bbase + w * 16 + q * 4 + r;
                out[(size_t)b * 8 + i0 + 0] = res[0][r];
                out[(size_t)b * 8 + i0 + 1] = res[1][r];
            }
        }

        __syncthreads();  // all waves done with fbS before next overwrite
    }
}

extern "C" void kernel_launch(void* const* d_in, const int* in_sizes, int n_in,
                              void* d_out, int out_size, void* d_ws, size_t ws_size,
                              hipStream_t stream) {
    (void)n_in; (void)out_size; (void)ws_size;
    const float* x = (const float*)d_in[0];
    const float* w = (const float*)d_in[1];
    float* out = (float*)d_out;
    char* ws = (char*)d_ws;
    float* E = (float*)(ws + WS_E_OFF);
    _Float16* Fb = (_Float16*)(ws + WS_FB_OFF);
    const int B = in_sizes[0] / 2;

    hipLaunchKernelGGL(qnn_grid_lds, dim3(NG2), dim3(256), 0, stream, w, E);
    hipLaunchKernelGGL(dft2, dim3(64, 8), dim3(64), 0, stream, E, Fb);
    hipLaunchKernelGGL(contract_mfma, dim3((B + 63) / 64, 1), dim3(256), 0, stream,
                       x, Fb, out, B);
}

// Round 3
// 108.108 us; speedup vs baseline: 1.1596x; 1.1596x over previous
//
#include <hip/hip_runtime.h>
#include <math.h>

#define N_WIRES 8
#define N_LAYERS 6
#define NG 49          // grid per axis (frequencies |n|<=24 -> 49 samples exact)
#define NG2 (NG * NG)  // 2401

// ws layout (bytes):
//   E  : [0, 76832)        8 x 2401 floats (grid EVs, [i][a*49+b])
//   Fb : [76832, +65536)   MFMA-B-fragment-ordered f16 F (pi folded):
//        frag fid=((i*4+ntile)*2+chunk): 64 lanes x 8 f16;
//        lane q*16+n, elem j  =  F_i[k=ntile*16+n][l=chunk*32+q*8+j]
//        (zero for k>=49 or l>=52)
#define WS_E_OFF 0
#define WS_FB_OFF 76832

typedef _Float16 half8 __attribute__((ext_vector_type(8)));
typedef float f32x4 __attribute__((ext_vector_type(4)));

// ---------------------------------------------------------------------------
// Grid circuit eval, block-per-point (round-1 structure: shfl for intra-wave
// wires, ping-pong LDS + 1 barrier for cross-wave exchanges). FROZEN.
// ---------------------------------------------------------------------------
__global__ __launch_bounds__(256) void qnn_grid_lds(const float* __restrict__ w,
                                                    float* __restrict__ E) {
    __shared__ float gates[N_LAYERS * N_WIRES * 8];
    __shared__ float2 bufA[256];
    __shared__ float2 bufB[256];
    __shared__ float partial[4][8];

    const int tid = threadIdx.x;
    const int g = blockIdx.x;
    const int ga = (g * 1338) >> 16;  // g/49, exact for g < 2404
    const int gb = g - ga * NG;
    const float step = (float)(2.0 * M_PI / 49.0);

    if (tid < N_LAYERS * N_WIRES) {
        const int i = tid & 7;
        float wx = w[tid * 3 + 0], wy = w[tid * 3 + 1], wz = w[tid * 3 + 2];
        float sx, cx, sy, cy, sz, cz;
        sincosf(0.5f * wx, &sx, &cx);
        sincosf(0.5f * wy, &sy, &cy);
        sincosf(0.5f * wz, &sz, &cz);
        float A00r = cy * cx, A00i = sy * sx;
        float A01r = -sy * cx, A01i = -cy * sx;
        float A10r = sy * cx, A10i = -cy * sx;
        float A11r = cy * cx, A11i = -sy * sx;
        float U00r = A00r * cz + A00i * sz, U00i = A00i * cz - A00r * sz;
        float U01r = A01r * cz + A01i * sz, U01i = A01i * cz - A01r * sz;
        float U10r = A10r * cz - A10i * sz, U10i = A10i * cz + A10r * sz;
        float U11r = A11r * cz - A11i * sz, U11i = A11i * cz + A11r * sz;
        float V00r, V00i, V01r, V01i, V10r, V10i, V11r, V11i;
        if ((i & 1) == 0) {
            V00r = U01i; V00i = -U01r;
            V01r = U00i; V01i = -U00r;
            V10r = U11i; V10i = -U11r;
            V11r = U10i; V11i = -U10r;
        } else {
            V00r = U01r;  V00i = U01i;
            V01r = -U00r; V01i = -U00i;
            V10r = U11r;  V10i = U11i;
            V11r = -U10r; V11i = -U10i;
        }
        const float xx = (i & 1) ? (step * (float)gb) : (step * (float)ga);
        float se, ce;
        sincosf(0.5f * xx, &se, &ce);
        float* o = gates + tid * 8;
        o[0] = ce * U00r + se * V00r;  o[1] = ce * U00i + se * V00i;
        o[2] = ce * U01r + se * V01r;  o[3] = ce * U01i + se * V01i;
        o[4] = ce * U10r + se * V10r;  o[5] = ce * U10i + se * V10i;
        o[6] = ce * U11r + se * V11r;  o[7] = ce * U11i + se * V11i;
    }

    float ar = (tid == 0) ? 1.0f : 0.0f;
    float ai = 0.0f;
    __syncthreads();

    int flip = 0;
    for (int l = 0; l < N_LAYERS; ++l) {
        #pragma unroll
        for (int i = 0; i < 2; ++i) {
            const float* gm = gates + (l * 8 + i) * 8;
            const int p = 7 - i;
            const int m = 1 << p;
            const int bit = (tid >> p) & 1;
            float2* buf = flip ? bufB : bufA;
            flip ^= 1;
            buf[tid] = make_float2(ar, ai);
            __syncthreads();
            float2 other = buf[tid ^ m];
            float a0r = bit ? other.x : ar, a0i = bit ? other.y : ai;
            float a1r = bit ? ar : other.x, a1i = bit ? ai : other.y;
            float c0r = gm[bit * 4 + 0], c0i = gm[bit * 4 + 1];
            float c1r = gm[bit * 4 + 2], c1i = gm[bit * 4 + 3];
            float nr = c0r * a0r - c0i * a0i + c1r * a1r - c1i * a1i;
            float ni = c0r * a0i + c0i * a0r + c1r * a1i + c1i * a1r;
            ar = nr; ai = ni;
        }
        #pragma unroll
        for (int i = 2; i < 8; ++i) {
            const float* gm = gates + (l * 8 + i) * 8;
            const int p = 7 - i;
            const int m = 1 << p;
            const int bit = (tid >> p) & 1;
            float otr = __shfl_xor(ar, m);
            float oti = __shfl_xor(ai, m);
            float a0r = bit ? otr : ar, a0i = bit ? oti : ai;
            float a1r = bit ? ar : otr, a1i = bit ? ai : oti;
            float c0r = gm[bit * 4 + 0], c0i = gm[bit * 4 + 1];
            float c1r = gm[bit * 4 + 2], c1i = gm[bit * 4 + 3];
            float nr = c0r * a0r - c0i * a0i + c1r * a1r - c1i * a1i;
            float ni = c0r * a0i + c0i * a0r + c1r * a1i + c1i * a1r;
            ar = nr; ai = ni;
        }
        {
            float2* buf = flip ? bufB : bufA;
            flip ^= 1;
            buf[tid] = make_float2(ar, ai);
            __syncthreads();
            float2 src = buf[tid ^ (tid >> 1)];
            ar = src.x; ai = src.y;
        }
    }

    float p = ar * ar + ai * ai;
    float ev[8];
    #pragma unroll
    for (int i = 0; i < 8; ++i) ev[i] = ((tid >> (7 - i)) & 1) ? -p : p;
    #pragma unroll
    for (int i = 0; i < 8; ++i) {
        #pragma unroll
        for (int s = 1; s < 64; s <<= 1) ev[i] += __shfl_xor(ev[i], s);
    }
    const int wave = tid >> 6, lane = tid & 63;
    if (lane == 0) {
        #pragma unroll
        for (int i = 0; i < 8; ++i) partial[wave][i] = ev[i];
    }
    __syncthreads();
    if (tid < 8) {
        E[tid * NG2 + g] = partial[0][tid] + partial[1][tid] + partial[2][tid] + partial[3][tid];
    }
}

// ---------------------------------------------------------------------------
// Fused separable 2D DFT writing MFMA-B-fragment-ordered f16 (round-1
// structure: exact mod-49 sincos table). FROZEN.
// ---------------------------------------------------------------------------
__global__ __launch_bounds__(64) void dft2(const float* __restrict__ E,
                                           _Float16* __restrict__ Fb) {
    const int kp = blockIdx.x, i = blockIdx.y, t = threadIdx.x;
    __shared__ float Es[NG2];
    __shared__ float H[NG];
    __shared__ float tc[NG], ts[NG];
    const float step = (float)(2.0 * M_PI / 49.0);
    const float PI = 3.14159265358979323846f;

    if (t < NG) {
        float s, c;
        sincosf(step * (float)t, &s, &c);
        tc[t] = c; ts[t] = s;
    }
    if (kp < NG) {
        for (int e = t; e < NG2; e += 64) Es[e] = E[i * NG2 + e];
    }
    __syncthreads();

    if (kp < NG && t < NG) {
        const int b = t;
        const int n = (kp + 1) >> 1;  // 0 for kp==0
        const bool use_cos = (kp & 1) || (kp == 0);
        float acc = 0.f;
        int j = 0;
        for (int a = 0; a < NG; ++a) {
            acc = fmaf(Es[a * NG + b], use_cos ? tc[j] : ts[j], acc);
            j += n; if (j >= NG) j -= NG;
        }
        acc *= (kp == 0) ? (1.0f / 49.0f) : (2.0f / 49.0f);
        H[b] = acc;
    }
    __syncthreads();

    const int l = t;
    float acc = 0.f;
    if (kp < NG && l < NG) {
        const int n = (l + 1) >> 1;  // 0 for l==0
        const bool use_cos = (l & 1) || (l == 0);
        int j = 0;
        for (int b = 0; b < NG; ++b) {
            acc = fmaf(H[b], use_cos ? tc[j] : ts[j], acc);
            j += n; if (j >= NG) j -= NG;
        }
        acc *= (l == 0) ? (PI / 49.0f) : (2.0f * PI / 49.0f);
    }
    {
        const int ntile = kp >> 4, n = kp & 15;
        const int chunk = l >> 5, lrem = l & 31;
        const int q = lrem >> 3, j = lrem & 7;
        const int fid = (i * 4 + ntile) * 2 + chunk;
        Fb[fid * 512 + (q * 16 + n) * 8 + j] = (_Float16)acc;
    }
}

// ---------------------------------------------------------------------------
// MFMA contraction. Round-3: revert round-2's LDS staging (it serialized on
// barriers and halved occupancy: 49 us vs 31). Back to direct L2-hot global
// bfrag loads + two latency fixes:
//   (1) v0 values hoisted out of the ip loop into 16 regs (they were
//       re-read from LDS identically every iteration: 128 -> 32 ds_read_b32
//       per thread).
//   (2) in-place software pipeline: ip+1's 16 bfrag loads issued right after
//       the current MFMA block, so L2 latency hides under the ~300-cycle
//       epilogue (WAR on the MFMA source regs orders it; no barriers, no
//       extra buffer).
// MFMA inputs/order byte-identical to round-1.
// ---------------------------------------------------------------------------
#define V0PAD 68

__global__ __launch_bounds__(256) void contract_mfma(const float* __restrict__ x,
                                                     const _Float16* __restrict__ Fb,
                                                     float* __restrict__ out, int B) {
    __shared__ float xs0[64], xs1[64];
    __shared__ float v0t[64 * V0PAD];  // 17.4 KB

    const int tid = threadIdx.x;
    const int bbase = blockIdx.x * 64;
    if (bbase >= B) return;

    if (tid < 64) {
        float2 xv = ((const float2*)x)[bbase + tid];
        xs0[tid] = xv.x;
        xs1[tid] = xv.y;
    }
    __syncthreads();

    // ---- v0 table: thread t -> batch b=t&63, k-segment s=t>>6 (16 k's) ----
    {
        const int b = tid & 63, s = tid >> 6;
        const float x0 = xs0[b];
        float c1, s1;
        sincosf(x0, &s1, &c1);
        float cb, sb;
        sincosf((float)(8 * s) * x0, &sb, &cb);
        float* row = v0t + b * V0PAD + 16 * s;
        const int k0 = 16 * s;
        row[0] = (k0 == 0) ? 1.0f : ((k0 < NG) ? sb : 0.0f);
        float cm = cb, sm = sb;
        #pragma unroll
        for (int j = 1; j < 16; ++j) {
            if (j & 1) {
                float c2 = cm * c1 - sm * s1, s2 = sm * c1 + cm * s1;
                cm = c2; sm = s2;
            }
            float val = (j & 1) ? cm : sm;
            row[j] = ((k0 + j) < NG) ? val : 0.0f;
        }
    }

    const int lane = tid & 63;
    const int w = tid >> 6;
    const int q = lane >> 4;

    // ---- A fragments (built once, reused for all 4 i-pairs) ----
    const float x1v = xs1[w * 16 + (lane & 15)];
    float c1, s1;
    sincosf(x1v, &s1, &c1);
    half8 afrag[2];
    #pragma unroll
    for (int c = 0; c < 2; ++c) {
        const int l0 = c * 32 + q * 8;
        float cb, sb;
        sincosf((float)(l0 >> 1) * x1v, &sb, &cb);
        float vals[8];
        vals[0] = (l0 == 0) ? 1.0f : sb;
        float cm = cb, sm = sb;
        #pragma unroll
        for (int j = 1; j < 8; ++j) {
            if (j & 1) {
                float c2 = cm * c1 - sm * s1, s2 = sm * c1 + cm * s1;
                cm = c2; sm = s2;
            }
            vals[j] = (j & 1) ? cm : sm;
        }
        #pragma unroll
        for (int j = 0; j < 8; ++j) {
            afrag[c][j] = (_Float16)(((l0 + j) < 52) ? vals[j] : 0.0f);
        }
    }

    __syncthreads();  // v0t ready

    // ---- (1) hoist the 16 v0 values (identical for all 4 ip iterations) ----
    float v0r[16];
    #pragma unroll
    for (int nt = 0; nt < 4; ++nt)
        #pragma unroll
        for (int r = 0; r < 4; ++r)
            v0r[nt * 4 + r] = v0t[(w * 16 + q * 4 + r) * V0PAD + nt * 16 + (lane & 15)];

    const half8* FB = (const half8*)Fb;

    // ---- preload ip=0's fragments ----
    half8 bfrag[16];
    #pragma unroll
    for (int f = 0; f < 16; ++f) bfrag[f] = FB[f * 64 + lane];

    #pragma unroll 1
    for (int ip = 0; ip < 4; ++ip) {
        const int i0 = ip * 2;

        f32x4 acc[8];
        #pragma unroll
        for (int t = 0; t < 8; ++t) {
            f32x4 z = {0.f, 0.f, 0.f, 0.f};
            acc[t] = __builtin_amdgcn_mfma_f32_16x16x32_f16(afrag[0], bfrag[t * 2 + 0], z, 0, 0, 0);
            acc[t] = __builtin_amdgcn_mfma_f32_16x16x32_f16(afrag[1], bfrag[t * 2 + 1], acc[t], 0, 0, 0);
        }

        // (2) issue next i-pair's loads now; latency hides under the epilogue
        if (ip < 3) {
            #pragma unroll
            for (int f = 0; f < 16; ++f)
                bfrag[f] = FB[((ip + 1) * 16 + f) * 64 + lane];
        }

        float res[2][4];
        #pragma unroll
        for (int ii = 0; ii < 2; ++ii)
            #pragma unroll
            for (int r = 0; r < 4; ++r) res[ii][r] = 0.f;

        #pragma unroll
        for (int ii = 0; ii < 2; ++ii)
            #pragma unroll
            for (int nt = 0; nt < 4; ++nt) {
                f32x4 a = acc[ii * 4 + nt];
                #pragma unroll
                for (int r = 0; r < 4; ++r) {
                    res[ii][r] = fmaf(a[r], v0r[nt * 4 + r], res[ii][r]);
                }
            }

        #pragma unroll
        for (int ii = 0; ii < 2; ++ii)
            #pragma unroll
            for (int r = 0; r < 4; ++r) {
                float v = res[ii][r];
                v += __shfl_xor(v, 1);
                v += __shfl_xor(v, 2);
                v += __shfl_xor(v, 4);
                v += __shfl_xor(v, 8);
                res[ii][r] = v;
            }

        if ((lane & 15) == 0) {
            #pragma unroll
            for (int r = 0; r < 4; ++r) {
                const int b = bbase + w * 16 + q * 4 + r;
                out[(size_t)b * 8 + i0 + 0] = res[0][r];
                out[(size_t)b * 8 + i0 + 1] = res[1][r];
            }
        }
    }
}

extern "C" void kernel_launch(void* const* d_in, const int* in_sizes, int n_in,
                              void* d_out, int out_size, void* d_ws, size_t ws_size,
                              hipStream_t stream) {
    (void)n_in; (void)out_size; (void)ws_size;
    const float* x = (const float*)d_in[0];
    const float* w = (const float*)d_in[1];
    float* out = (float*)d_out;
    char* ws = (char*)d_ws;
    float* E = (float*)(ws + WS_E_OFF);
    _Float16* Fb = (_Float16*)(ws + WS_FB_OFF);
    const int B = in_sizes[0] / 2;

    hipLaunchKernelGGL(qnn_grid_lds, dim3(NG2), dim3(256), 0, stream, w, E);
    hipLaunchKernelGGL(dft2, dim3(64, 8), dim3(64), 0, stream, E, Fb);
    hipLaunchKernelGGL(contract_mfma, dim3((B + 63) / 64, 1), dim3(256), 0, stream,
                       x, Fb, out, B);
}

// Round 4
// 103.821 us; speedup vs baseline: 1.2074x; 1.0413x over previous
//
#include <hip/hip_runtime.h>
#include <math.h>

#define N_WIRES 8
#define N_LAYERS 6
#define NG 49          // grid per axis (frequencies |n|<=24 -> 49 samples exact)
#define NG2 (NG * NG)  // 2401

// ws layout (bytes):
//   E  : [0, 76832)        8 x 2401 floats (grid EVs, [i][a*49+b])
//   Fb : [76832, +65536)   MFMA-B-fragment-ordered f16 F (pi folded):
//        frag fid=((i*4+ntile)*2+chunk): 64 lanes x 8 f16;
//        lane q*16+n, elem j  =  F_i[k=ntile*16+n][l=chunk*32+q*8+j]
//        (zero for k>=49 or l>=52)
#define WS_E_OFF 0
#define WS_FB_OFF 76832

typedef _Float16 half8 __attribute__((ext_vector_type(8)));
typedef float f32x4 __attribute__((ext_vector_type(4)));

// ---------------------------------------------------------------------------
// Grid circuit eval, block-per-point (round-1 structure). FROZEN.
// ---------------------------------------------------------------------------
__global__ __launch_bounds__(256) void qnn_grid_lds(const float* __restrict__ w,
                                                    float* __restrict__ E) {
    __shared__ float gates[N_LAYERS * N_WIRES * 8];
    __shared__ float2 bufA[256];
    __shared__ float2 bufB[256];
    __shared__ float partial[4][8];

    const int tid = threadIdx.x;
    const int g = blockIdx.x;
    const int ga = (g * 1338) >> 16;  // g/49, exact for g < 2404
    const int gb = g - ga * NG;
    const float step = (float)(2.0 * M_PI / 49.0);

    if (tid < N_LAYERS * N_WIRES) {
        const int i = tid & 7;
        float wx = w[tid * 3 + 0], wy = w[tid * 3 + 1], wz = w[tid * 3 + 2];
        float sx, cx, sy, cy, sz, cz;
        sincosf(0.5f * wx, &sx, &cx);
        sincosf(0.5f * wy, &sy, &cy);
        sincosf(0.5f * wz, &sz, &cz);
        float A00r = cy * cx, A00i = sy * sx;
        float A01r = -sy * cx, A01i = -cy * sx;
        float A10r = sy * cx, A10i = -cy * sx;
        float A11r = cy * cx, A11i = -sy * sx;
        float U00r = A00r * cz + A00i * sz, U00i = A00i * cz - A00r * sz;
        float U01r = A01r * cz + A01i * sz, U01i = A01i * cz - A01r * sz;
        float U10r = A10r * cz - A10i * sz, U10i = A10i * cz + A10r * sz;
        float U11r = A11r * cz - A11i * sz, U11i = A11i * cz + A11r * sz;
        float V00r, V00i, V01r, V01i, V10r, V10i, V11r, V11i;
        if ((i & 1) == 0) {
            V00r = U01i; V00i = -U01r;
            V01r = U00i; V01i = -U00r;
            V10r = U11i; V10i = -U11r;
            V11r = U10i; V11i = -U10r;
        } else {
            V00r = U01r;  V00i = U01i;
            V01r = -U00r; V01i = -U00i;
            V10r = U11r;  V10i = U11i;
            V11r = -U10r; V11i = -U10i;
        }
        const float xx = (i & 1) ? (step * (float)gb) : (step * (float)ga);
        float se, ce;
        sincosf(0.5f * xx, &se, &ce);
        float* o = gates + tid * 8;
        o[0] = ce * U00r + se * V00r;  o[1] = ce * U00i + se * V00i;
        o[2] = ce * U01r + se * V01r;  o[3] = ce * U01i + se * V01i;
        o[4] = ce * U10r + se * V10r;  o[5] = ce * U10i + se * V10i;
        o[6] = ce * U11r + se * V11r;  o[7] = ce * U11i + se * V11i;
    }

    float ar = (tid == 0) ? 1.0f : 0.0f;
    float ai = 0.0f;
    __syncthreads();

    int flip = 0;
    for (int l = 0; l < N_LAYERS; ++l) {
        #pragma unroll
        for (int i = 0; i < 2; ++i) {
            const float* gm = gates + (l * 8 + i) * 8;
            const int p = 7 - i;
            const int m = 1 << p;
            const int bit = (tid >> p) & 1;
            float2* buf = flip ? bufB : bufA;
            flip ^= 1;
            buf[tid] = make_float2(ar, ai);
            __syncthreads();
            float2 other = buf[tid ^ m];
            float a0r = bit ? other.x : ar, a0i = bit ? other.y : ai;
            float a1r = bit ? ar : other.x, a1i = bit ? ai : other.y;
            float c0r = gm[bit * 4 + 0], c0i = gm[bit * 4 + 1];
            float c1r = gm[bit * 4 + 2], c1i = gm[bit * 4 + 3];
            float nr = c0r * a0r - c0i * a0i + c1r * a1r - c1i * a1i;
            float ni = c0r * a0i + c0i * a0r + c1r * a1i + c1i * a1r;
            ar = nr; ai = ni;
        }
        #pragma unroll
        for (int i = 2; i < 8; ++i) {
            const float* gm = gates + (l * 8 + i) * 8;
            const int p = 7 - i;
            const int m = 1 << p;
            const int bit = (tid >> p) & 1;
            float otr = __shfl_xor(ar, m);
            float oti = __shfl_xor(ai, m);
            float a0r = bit ? otr : ar, a0i = bit ? oti : ai;
            float a1r = bit ? ar : otr, a1i = bit ? ai : oti;
            float c0r = gm[bit * 4 + 0], c0i = gm[bit * 4 + 1];
            float c1r = gm[bit * 4 + 2], c1i = gm[bit * 4 + 3];
            float nr = c0r * a0r - c0i * a0i + c1r * a1r - c1i * a1i;
            float ni = c0r * a0i + c0i * a0r + c1r * a1i + c1i * a1r;
            ar = nr; ai = ni;
        }
        {
            float2* buf = flip ? bufB : bufA;
            flip ^= 1;
            buf[tid] = make_float2(ar, ai);
            __syncthreads();
            float2 src = buf[tid ^ (tid >> 1)];
            ar = src.x; ai = src.y;
        }
    }

    float p = ar * ar + ai * ai;
    float ev[8];
    #pragma unroll
    for (int i = 0; i < 8; ++i) ev[i] = ((tid >> (7 - i)) & 1) ? -p : p;
    #pragma unroll
    for (int i = 0; i < 8; ++i) {
        #pragma unroll
        for (int s = 1; s < 64; s <<= 1) ev[i] += __shfl_xor(ev[i], s);
    }
    const int wave = tid >> 6, lane = tid & 63;
    if (lane == 0) {
        #pragma unroll
        for (int i = 0; i < 8; ++i) partial[wave][i] = ev[i];
    }
    __syncthreads();
    if (tid < 8) {
        E[tid * NG2 + g] = partial[0][tid] + partial[1][tid] + partial[2][tid] + partial[3][tid];
    }
}

// ---------------------------------------------------------------------------
// Fused separable 2D DFT (round-1 structure: exact mod-49 table). FROZEN.
// ---------------------------------------------------------------------------
__global__ __launch_bounds__(64) void dft2(const float* __restrict__ E,
                                           _Float16* __restrict__ Fb) {
    const int kp = blockIdx.x, i = blockIdx.y, t = threadIdx.x;
    __shared__ float Es[NG2];
    __shared__ float H[NG];
    __shared__ float tc[NG], ts[NG];
    const float step = (float)(2.0 * M_PI / 49.0);
    const float PI = 3.14159265358979323846f;

    if (t < NG) {
        float s, c;
        sincosf(step * (float)t, &s, &c);
        tc[t] = c; ts[t] = s;
    }
    if (kp < NG) {
        for (int e = t; e < NG2; e += 64) Es[e] = E[i * NG2 + e];
    }
    __syncthreads();

    if (kp < NG && t < NG) {
        const int b = t;
        const int n = (kp + 1) >> 1;  // 0 for kp==0
        const bool use_cos = (kp & 1) || (kp == 0);
        float acc = 0.f;
        int j = 0;
        for (int a = 0; a < NG; ++a) {
            acc = fmaf(Es[a * NG + b], use_cos ? tc[j] : ts[j], acc);
            j += n; if (j >= NG) j -= NG;
        }
        acc *= (kp == 0) ? (1.0f / 49.0f) : (2.0f / 49.0f);
        H[b] = acc;
    }
    __syncthreads();

    const int l = t;
    float acc = 0.f;
    if (kp < NG && l < NG) {
        const int n = (l + 1) >> 1;  // 0 for l==0
        const bool use_cos = (l & 1) || (l == 0);
        int j = 0;
        for (int b = 0; b < NG; ++b) {
            acc = fmaf(H[b], use_cos ? tc[j] : ts[j], acc);
            j += n; if (j >= NG) j -= NG;
        }
        acc *= (l == 0) ? (PI / 49.0f) : (2.0f * PI / 49.0f);
    }
    {
        const int ntile = kp >> 4, n = kp & 15;
        const int chunk = l >> 5, lrem = l & 31;
        const int q = lrem >> 3, j = lrem & 7;
        const int fid = (i * 4 + ntile) * 2 + chunk;
        Fb[fid * 512 + (q * 16 + n) * 8 + j] = (_Float16)acc;
    }
}

// ---------------------------------------------------------------------------
// MFMA contraction, round-4: wave<->work binding inverted. Wave w owns
// i-pair w; its 16 B-fragments are loaded from global ONCE (issued at kernel
// top, latency hidden under the sincos build phase) and stay in VGPRs for
// the whole kernel -> Fb L2 traffic 512 MB -> 128 MB, zero barriers in the
// main loop. The wave loops over the 4 batch-groups; A-fragments (built per
// thread for its own batch, as before) cross waves via an 8 KB LDS stage in
// the canonical contiguous [c][bg][lane]x16B layout (conflict-free
// ds_write/ds_read_b128). MFMA inputs bit-identical to round-3.
// ---------------------------------------------------------------------------
#define V0PAD 68

__global__ __launch_bounds__(256) void contract_mfma(const float* __restrict__ x,
                                                     const _Float16* __restrict__ Fb,
                                                     float* __restrict__ out, int B) {
    __shared__ float xs0[64], xs1[64];
    __shared__ float v0t[64 * V0PAD];              // 17.4 KB
    __shared__ __align__(16) half8 aS[2 * 4 * 64]; // 8 KB: [c][bg][lane]

    const int tid = threadIdx.x;
    const int bbase = blockIdx.x * 64;
    if (bbase >= B) return;

    const int lane = tid & 63;
    const int w = tid >> 6;
    const int q = lane >> 4;

    // ---- issue this wave's 16 resident B-fragment loads NOW; latency
    //      hides under the sincos-heavy build phase below ----
    const half8* FB = (const half8*)Fb;
    half8 bfrag[16];
    #pragma unroll
    for (int f = 0; f < 16; ++f) bfrag[f] = FB[(w * 16 + f) * 64 + lane];

    if (tid < 64) {
        float2 xv = ((const float2*)x)[bbase + tid];
        xs0[tid] = xv.x;
        xs1[tid] = xv.y;
    }
    __syncthreads();

    // ---- v0 table: thread t -> batch b=t&63, k-segment s=t>>6 (16 k's) ----
    {
        const int b = tid & 63, s = tid >> 6;
        const float x0 = xs0[b];
        float c1, s1;
        sincosf(x0, &s1, &c1);
        float cb, sb;
        sincosf((float)(8 * s) * x0, &sb, &cb);
        float* row = v0t + b * V0PAD + 16 * s;
        const int k0 = 16 * s;
        row[0] = (k0 == 0) ? 1.0f : ((k0 < NG) ? sb : 0.0f);
        float cm = cb, sm = sb;
        #pragma unroll
        for (int j = 1; j < 16; ++j) {
            if (j & 1) {
                float c2 = cm * c1 - sm * s1, s2 = sm * c1 + cm * s1;
                cm = c2; sm = s2;
            }
            float val = (j & 1) ? cm : sm;
            row[j] = ((k0 + j) < NG) ? val : 0.0f;
        }
    }

    // ---- A fragments for THIS thread's batch, staged to LDS so every wave
    //      can read every batch-group's A ----
    {
        const float x1v = xs1[w * 16 + (lane & 15)];
        float c1, s1;
        sincosf(x1v, &s1, &c1);
        #pragma unroll
        for (int c = 0; c < 2; ++c) {
            const int l0 = c * 32 + q * 8;
            float cb, sb;
            sincosf((float)(l0 >> 1) * x1v, &sb, &cb);
            float vals[8];
            vals[0] = (l0 == 0) ? 1.0f : sb;
            float cm = cb, sm = sb;
            #pragma unroll
            for (int j = 1; j < 8; ++j) {
                if (j & 1) {
                    float c2 = cm * c1 - sm * s1, s2 = sm * c1 + cm * s1;
                    cm = c2; sm = s2;
                }
                vals[j] = (j & 1) ? cm : sm;
            }
            half8 af;
            #pragma unroll
            for (int j = 0; j < 8; ++j) {
                af[j] = (_Float16)(((l0 + j) < 52) ? vals[j] : 0.0f);
            }
            aS[(c * 4 + w) * 64 + lane] = af;
        }
    }

    __syncthreads();  // v0t + aS ready; bfrag loads drained by barrier's vmcnt(0)

    // ---- main loop: wave w = i-pair w, iterate batch-groups. NO barriers. ----
    #pragma unroll 1
    for (int bg = 0; bg < 4; ++bg) {
        const half8 a0 = aS[(0 * 4 + bg) * 64 + lane];
        const half8 a1 = aS[(1 * 4 + bg) * 64 + lane];

        f32x4 acc[8];
        #pragma unroll
        for (int t = 0; t < 8; ++t) {
            f32x4 z = {0.f, 0.f, 0.f, 0.f};
            acc[t] = __builtin_amdgcn_mfma_f32_16x16x32_f16(a0, bfrag[t * 2 + 0], z, 0, 0, 0);
            acc[t] = __builtin_amdgcn_mfma_f32_16x16x32_f16(a1, bfrag[t * 2 + 1], acc[t], 0, 0, 0);
        }

        float res[2][4];
        #pragma unroll
        for (int ii = 0; ii < 2; ++ii)
            #pragma unroll
            for (int r = 0; r < 4; ++r) res[ii][r] = 0.f;

        #pragma unroll
        for (int ii = 0; ii < 2; ++ii)
            #pragma unroll
            for (int nt = 0; nt < 4; ++nt) {
                f32x4 a = acc[ii * 4 + nt];
                #pragma unroll
                for (int r = 0; r < 4; ++r) {
                    const int bloc = bg * 16 + q * 4 + r;
                    float v0 = v0t[bloc * V0PAD + nt * 16 + (lane & 15)];
                    res[ii][r] = fmaf(a[r], v0, res[ii][r]);
                }
            }

        #pragma unroll
        for (int ii = 0; ii < 2; ++ii)
            #pragma unroll
            for (int r = 0; r < 4; ++r) {
                float v = res[ii][r];
                v += __shfl_xor(v, 1);
                v += __shfl_xor(v, 2);
                v += __shfl_xor(v, 4);
                v += __shfl_xor(v, 8);
                res[ii][r] = v;
            }

        if ((lane & 15) == 0) {
            #pragma unroll
            for (int r = 0; r < 4; ++r) {
                const int b = bbase + bg * 16 + q * 4 + r;
                float2 st = make_float2(res[0][r], res[1][r]);
                *(float2*)&out[(size_t)b * 8 + 2 * w] = st;
            }
        }
    }
}

extern "C" void kernel_launch(void* const* d_in, const int* in_sizes, int n_in,
                              void* d_out, int out_size, void* d_ws, size_t ws_size,
                              hipStream_t stream) {
    (void)n_in; (void)out_size; (void)ws_size;
    const float* x = (const float*)d_in[0];
    const float* w = (const float*)d_in[1];
    float* out = (float*)d_out;
    char* ws = (char*)d_ws;
    float* E = (float*)(ws + WS_E_OFF);
    _Float16* Fb = (_Float16*)(ws + WS_FB_OFF);
    const int B = in_sizes[0] / 2;

    hipLaunchKernelGGL(qnn_grid_lds, dim3(NG2), dim3(256), 0, stream, w, E);
    hipLaunchKernelGGL(dft2, dim3(64, 8), dim3(64), 0, stream, E, Fb);
    hipLaunchKernelGGL(contract_mfma, dim3((B + 63) / 64, 1), dim3(256), 0, stream,
                       x, Fb, out, B);
}

// Round 5
// 96.472 us; speedup vs baseline: 1.2994x; 1.0762x over previous
//
#include <hip/hip_runtime.h>
#include <math.h>

#define N_WIRES 8
#define N_LAYERS 6
#define NG 49          // grid per axis (frequencies |n|<=24 -> 49 samples exact)
#define NG2 (NG * NG)  // 2401

// ws layout (bytes):
//   E  : [0, 76832)        8 x 2401 floats (grid EVs, [i][a*49+b])
//   Fb : [76832, +65536)   MFMA-B-fragment-ordered f16 F (pi folded):
//        frag fid=((i*4+ntile)*2+chunk): 64 lanes x 8 f16;
//        lane q*16+n, elem j  =  F_i[k=ntile*16+n][l=chunk*32+q*8+j]
//        (zero for k>=49 or l>=52)
#define WS_E_OFF 0
#define WS_FB_OFF 76832

typedef _Float16 half8 __attribute__((ext_vector_type(8)));
typedef float f32x4 __attribute__((ext_vector_type(4)));

// ---------------------------------------------------------------------------
// DPP-based 16-lane-row sum: quad_perm xor1/xor2 then row_ror 4/8.
// Pure VALU (v_add_f32_dpp) -- replaces 4 ds_swizzle per value. Every lane
// ends with the full 16-lane sum (rotation-reduce, valid for commutative +).
// ---------------------------------------------------------------------------
__device__ __forceinline__ float row16_sum(float v) {
    v += __int_as_float(__builtin_amdgcn_update_dpp(
        0, __float_as_int(v), 0xB1, 0xF, 0xF, true));   // quad_perm [1,0,3,2]
    v += __int_as_float(__builtin_amdgcn_update_dpp(
        0, __float_as_int(v), 0x4E, 0xF, 0xF, true));   // quad_perm [2,3,0,1]
    v += __int_as_float(__builtin_amdgcn_update_dpp(
        0, __float_as_int(v), 0x124, 0xF, 0xF, true));  // row_ror:4
    v += __int_as_float(__builtin_amdgcn_update_dpp(
        0, __float_as_int(v), 0x128, 0xF, 0xF, true));  // row_ror:8
    return v;
}

// ---------------------------------------------------------------------------
// Grid circuit eval, block-per-point (round-1 structure). Only change:
// final 64-lane reduce uses row16_sum + 2 shfl instead of 6 shfl.
// ---------------------------------------------------------------------------
__global__ __launch_bounds__(256) void qnn_grid_lds(const float* __restrict__ w,
                                                    float* __restrict__ E) {
    __shared__ float gates[N_LAYERS * N_WIRES * 8];
    __shared__ float2 bufA[256];
    __shared__ float2 bufB[256];
    __shared__ float partial[4][8];

    const int tid = threadIdx.x;
    const int g = blockIdx.x;
    const int ga = (g * 1338) >> 16;  // g/49, exact for g < 2404
    const int gb = g - ga * NG;
    const float step = (float)(2.0 * M_PI / 49.0);

    if (tid < N_LAYERS * N_WIRES) {
        const int i = tid & 7;
        float wx = w[tid * 3 + 0], wy = w[tid * 3 + 1], wz = w[tid * 3 + 2];
        float sx, cx, sy, cy, sz, cz;
        sincosf(0.5f * wx, &sx, &cx);
        sincosf(0.5f * wy, &sy, &cy);
        sincosf(0.5f * wz, &sz, &cz);
        float A00r = cy * cx, A00i = sy * sx;
        float A01r = -sy * cx, A01i = -cy * sx;
        float A10r = sy * cx, A10i = -cy * sx;
        float A11r = cy * cx, A11i = -sy * sx;
        float U00r = A00r * cz + A00i * sz, U00i = A00i * cz - A00r * sz;
        float U01r = A01r * cz + A01i * sz, U01i = A01i * cz - A01r * sz;
        float U10r = A10r * cz - A10i * sz, U10i = A10i * cz + A10r * sz;
        float U11r = A11r * cz - A11i * sz, U11i = A11i * cz + A11r * sz;
        float V00r, V00i, V01r, V01i, V10r, V10i, V11r, V11i;
        if ((i & 1) == 0) {
            V00r = U01i; V00i = -U01r;
            V01r = U00i; V01i = -U00r;
            V10r = U11i; V10i = -U11r;
            V11r = U10i; V11i = -U10r;
        } else {
            V00r = U01r;  V00i = U01i;
            V01r = -U00r; V01i = -U00i;
            V10r = U11r;  V10i = U11i;
            V11r = -U10r; V11i = -U10i;
        }
        const float xx = (i & 1) ? (step * (float)gb) : (step * (float)ga);
        float se, ce;
        sincosf(0.5f * xx, &se, &ce);
        float* o = gates + tid * 8;
        o[0] = ce * U00r + se * V00r;  o[1] = ce * U00i + se * V00i;
        o[2] = ce * U01r + se * V01r;  o[3] = ce * U01i + se * V01i;
        o[4] = ce * U10r + se * V10r;  o[5] = ce * U10i + se * V10i;
        o[6] = ce * U11r + se * V11r;  o[7] = ce * U11i + se * V11i;
    }

    float ar = (tid == 0) ? 1.0f : 0.0f;
    float ai = 0.0f;
    __syncthreads();

    int flip = 0;
    for (int l = 0; l < N_LAYERS; ++l) {
        #pragma unroll
        for (int i = 0; i < 2; ++i) {
            const float* gm = gates + (l * 8 + i) * 8;
            const int p = 7 - i;
            const int m = 1 << p;
            const int bit = (tid >> p) & 1;
            float2* buf = flip ? bufB : bufA;
            flip ^= 1;
            buf[tid] = make_float2(ar, ai);
            __syncthreads();
            float2 other = buf[tid ^ m];
            float a0r = bit ? other.x : ar, a0i = bit ? other.y : ai;
            float a1r = bit ? ar : other.x, a1i = bit ? ai : other.y;
            float c0r = gm[bit * 4 + 0], c0i = gm[bit * 4 + 1];
            float c1r = gm[bit * 4 + 2], c1i = gm[bit * 4 + 3];
            float nr = c0r * a0r - c0i * a0i + c1r * a1r - c1i * a1i;
            float ni = c0r * a0i + c0i * a0r + c1r * a1i + c1i * a1r;
            ar = nr; ai = ni;
        }
        #pragma unroll
        for (int i = 2; i < 8; ++i) {
            const float* gm = gates + (l * 8 + i) * 8;
            const int p = 7 - i;
            const int m = 1 << p;
            const int bit = (tid >> p) & 1;
            float otr = __shfl_xor(ar, m);
            float oti = __shfl_xor(ai, m);
            float a0r = bit ? otr : ar, a0i = bit ? oti : ai;
            float a1r = bit ? ar : otr, a1i = bit ? ai : oti;
            float c0r = gm[bit * 4 + 0], c0i = gm[bit * 4 + 1];
            float c1r = gm[bit * 4 + 2], c1i = gm[bit * 4 + 3];
            float nr = c0r * a0r - c0i * a0i + c1r * a1r - c1i * a1i;
            float ni = c0r * a0i + c0i * a0r + c1r * a1i + c1i * a1r;
            ar = nr; ai = ni;
        }
        {
            float2* buf = flip ? bufB : bufA;
            flip ^= 1;
            buf[tid] = make_float2(ar, ai);
            __syncthreads();
            float2 src = buf[tid ^ (tid >> 1)];
            ar = src.x; ai = src.y;
        }
    }

    float p = ar * ar + ai * ai;
    float ev[8];
    #pragma unroll
    for (int i = 0; i < 8; ++i) ev[i] = ((tid >> (7 - i)) & 1) ? -p : p;
    #pragma unroll
    for (int i = 0; i < 8; ++i) {
        float v = row16_sum(ev[i]);
        v += __shfl_xor(v, 16);
        v += __shfl_xor(v, 32);
        ev[i] = v;
    }
    const int wave = tid >> 6, lane = tid & 63;
    if (lane == 0) {
        #pragma unroll
        for (int i = 0; i < 8; ++i) partial[wave][i] = ev[i];
    }
    __syncthreads();
    if (tid < 8) {
        E[tid * NG2 + g] = partial[0][tid] + partial[1][tid] + partial[2][tid] + partial[3][tid];
    }
}

// ---------------------------------------------------------------------------
// Fused separable 2D DFT (round-1 structure: exact mod-49 table). FROZEN.
// ---------------------------------------------------------------------------
__global__ __launch_bounds__(64) void dft2(const float* __restrict__ E,
                                           _Float16* __restrict__ Fb) {
    const int kp = blockIdx.x, i = blockIdx.y, t = threadIdx.x;
    __shared__ float Es[NG2];
    __shared__ float H[NG];
    __shared__ float tc[NG], ts[NG];
    const float step = (float)(2.0 * M_PI / 49.0);
    const float PI = 3.14159265358979323846f;

    if (t < NG) {
        float s, c;
        sincosf(step * (float)t, &s, &c);
        tc[t] = c; ts[t] = s;
    }
    if (kp < NG) {
        for (int e = t; e < NG2; e += 64) Es[e] = E[i * NG2 + e];
    }
    __syncthreads();

    if (kp < NG && t < NG) {
        const int b = t;
        const int n = (kp + 1) >> 1;  // 0 for kp==0
        const bool use_cos = (kp & 1) || (kp == 0);
        float acc = 0.f;
        int j = 0;
        for (int a = 0; a < NG; ++a) {
            acc = fmaf(Es[a * NG + b], use_cos ? tc[j] : ts[j], acc);
            j += n; if (j >= NG) j -= NG;
        }
        acc *= (kp == 0) ? (1.0f / 49.0f) : (2.0f / 49.0f);
        H[b] = acc;
    }
    __syncthreads();

    const int l = t;
    float acc = 0.f;
    if (kp < NG && l < NG) {
        const int n = (l + 1) >> 1;  // 0 for l==0
        const bool use_cos = (l & 1) || (l == 0);
        int j = 0;
        for (int b = 0; b < NG; ++b) {
            acc = fmaf(H[b], use_cos ? tc[j] : ts[j], acc);
            j += n; if (j >= NG) j -= NG;
        }
        acc *= (l == 0) ? (PI / 49.0f) : (2.0f * PI / 49.0f);
    }
    {
        const int ntile = kp >> 4, n = kp & 15;
        const int chunk = l >> 5, lrem = l & 31;
        const int q = lrem >> 3, j = lrem & 7;
        const int fid = (i * 4 + ntile) * 2 + chunk;
        Fb[fid * 512 + (q * 16 + n) * 8 + j] = (_Float16)acc;
    }
}

// ---------------------------------------------------------------------------
// MFMA contraction, round-5: round-4 skeleton (wave w owns i-pair w, resident
// B-frags, A via LDS, no main-loop barriers) + two instruction-cost fixes:
//   (1) 5 sincosf/thread -> 2: jump-point angles are integer multiples of the
//       base angle, derived via double-angle/angle-addition chains (~20 VALU
//       ops replace ~100+-inst libm calls).
//   (2) epilogue 16-lane reductions via DPP (row16_sum, VALU pipe) instead of
//       128 ds_swizzle ops on the shared LDS pipe.
// ---------------------------------------------------------------------------
#define V0PAD 68

__global__ __launch_bounds__(256) void contract_mfma(const float* __restrict__ x,
                                                     const _Float16* __restrict__ Fb,
                                                     float* __restrict__ out, int B) {
    __shared__ float xs0[64], xs1[64];
    __shared__ float v0t[64 * V0PAD];              // 17.4 KB
    __shared__ __align__(16) half8 aS[2 * 4 * 64]; // 8 KB: [c][bg][lane]

    const int tid = threadIdx.x;
    const int bbase = blockIdx.x * 64;
    if (bbase >= B) return;

    const int lane = tid & 63;
    const int w = tid >> 6;
    const int q = lane >> 4;

    // ---- issue this wave's 16 resident B-fragment loads NOW; latency
    //      hides under the build phase below ----
    const half8* FB = (const half8*)Fb;
    half8 bfrag[16];
    #pragma unroll
    for (int f = 0; f < 16; ++f) bfrag[f] = FB[(w * 16 + f) * 64 + lane];

    if (tid < 64) {
        float2 xv = ((const float2*)x)[bbase + tid];
        xs0[tid] = xv.x;
        xs1[tid] = xv.y;
    }
    __syncthreads();

    // ---- v0 table: thread t -> batch b=t&63, k-segment s=t>>6 (16 k's) ----
    {
        const int b = tid & 63, s = tid >> 6;
        const float x0 = xs0[b];
        float c1, s1;
        sincosf(x0, &s1, &c1);
        // derive sincos(8*s*x0) from (s1,c1): double-angle chain (was sincosf)
        float s2v = 2.f * s1 * c1, c2v = 1.f - 2.f * s1 * s1;
        float s4v = 2.f * s2v * c2v, c4v = 1.f - 2.f * s2v * s2v;
        float s8v = 2.f * s4v * c4v, c8v = 1.f - 2.f * s4v * s4v;
        float sb, cb;
        if (s == 0) {            // wave-uniform branch (s = tid>>6)
            sb = 0.f; cb = 1.f;
        } else if (s == 1) {
            sb = s8v; cb = c8v;
        } else if (s == 2) {
            sb = 2.f * s8v * c8v; cb = 1.f - 2.f * s8v * s8v;
        } else {
            float s16v = 2.f * s8v * c8v, c16v = 1.f - 2.f * s8v * s8v;
            sb = s16v * c8v + c16v * s8v; cb = c16v * c8v - s16v * s8v;
        }
        float* row = v0t + b * V0PAD + 16 * s;
        const int k0 = 16 * s;
        row[0] = (k0 == 0) ? 1.0f : ((k0 < NG) ? sb : 0.0f);
        float cm = cb, sm = sb;
        #pragma unroll
        for (int j = 1; j < 16; ++j) {
            if (j & 1) {
                float c2 = cm * c1 - sm * s1, s2 = sm * c1 + cm * s1;
                cm = c2; sm = s2;
            }
            float val = (j & 1) ? cm : sm;
            row[j] = ((k0 + j) < NG) ? val : 0.0f;
        }
    }

    // ---- A fragments for THIS thread's batch, staged to LDS ----
    {
        const float x1v = xs1[w * 16 + (lane & 15)];
        float c1, s1;
        sincosf(x1v, &s1, &c1);
        // jump points (16c+4q)*x1 derived from (s1,c1) (was 2x sincosf)
        float s2v = 2.f * s1 * c1, c2v = 1.f - 2.f * s1 * s1;
        float s4v = 2.f * s2v * c2v, c4v = 1.f - 2.f * s2v * s2v;
        float s8v = 2.f * s4v * c4v, c8v = 1.f - 2.f * s4v * s4v;
        float s12v = s8v * c4v + c8v * s4v, c12v = c8v * c4v - s8v * s4v;
        float sq = (q == 0) ? 0.f : ((q == 1) ? s4v : ((q == 2) ? s8v : s12v));
        float cq = (q == 0) ? 1.f : ((q == 1) ? c4v : ((q == 2) ? c8v : c12v));
        float s16v = 2.f * s8v * c8v, c16v = 1.f - 2.f * s8v * s8v;
        float sb_c[2], cb_c[2];
        sb_c[0] = sq;                      cb_c[0] = cq;
        sb_c[1] = sq * c16v + cq * s16v;   cb_c[1] = cq * c16v - sq * s16v;
        #pragma unroll
        for (int c = 0; c < 2; ++c) {
            const int l0 = c * 32 + q * 8;
            float cb = cb_c[c], sb = sb_c[c];
            float vals[8];
            vals[0] = (l0 == 0) ? 1.0f : sb;
            float cm = cb, sm = sb;
            #pragma unroll
            for (int j = 1; j < 8; ++j) {
                if (j & 1) {
                    float c2 = cm * c1 - sm * s1, s2 = sm * c1 + cm * s1;
                    cm = c2; sm = s2;
                }
                vals[j] = (j & 1) ? cm : sm;
            }
            half8 af;
            #pragma unroll
            for (int j = 0; j < 8; ++j) {
                af[j] = (_Float16)(((l0 + j) < 52) ? vals[j] : 0.0f);
            }
            aS[(c * 4 + w) * 64 + lane] = af;
        }
    }

    __syncthreads();  // v0t + aS ready; bfrag loads drained by barrier's vmcnt(0)

    // ---- main loop: wave w = i-pair w, iterate batch-groups. NO barriers. ----
    #pragma unroll 1
    for (int bg = 0; bg < 4; ++bg) {
        const half8 a0 = aS[(0 * 4 + bg) * 64 + lane];
        const half8 a1 = aS[(1 * 4 + bg) * 64 + lane];

        f32x4 acc[8];
        #pragma unroll
        for (int t = 0; t < 8; ++t) {
            f32x4 z = {0.f, 0.f, 0.f, 0.f};
            acc[t] = __builtin_amdgcn_mfma_f32_16x16x32_f16(a0, bfrag[t * 2 + 0], z, 0, 0, 0);
            acc[t] = __builtin_amdgcn_mfma_f32_16x16x32_f16(a1, bfrag[t * 2 + 1], acc[t], 0, 0, 0);
        }

        float res[2][4];
        #pragma unroll
        for (int ii = 0; ii < 2; ++ii)
            #pragma unroll
            for (int r = 0; r < 4; ++r) res[ii][r] = 0.f;

        #pragma unroll
        for (int ii = 0; ii < 2; ++ii)
            #pragma unroll
            for (int nt = 0; nt < 4; ++nt) {
                f32x4 a = acc[ii * 4 + nt];
                #pragma unroll
                for (int r = 0; r < 4; ++r) {
                    const int bloc = bg * 16 + q * 4 + r;
                    float v0 = v0t[bloc * V0PAD + nt * 16 + (lane & 15)];
                    res[ii][r] = fmaf(a[r], v0, res[ii][r]);
                }
            }

        #pragma unroll
        for (int ii = 0; ii < 2; ++ii)
            #pragma unroll
            for (int r = 0; r < 4; ++r) {
                res[ii][r] = row16_sum(res[ii][r]);  // DPP, no LDS pipe
            }

        if ((lane & 15) == 0) {
            #pragma unroll
            for (int r = 0; r < 4; ++r) {
                const int b = bbase + bg * 16 + q * 4 + r;
                float2 st = make_float2(res[0][r], res[1][r]);
                *(float2*)&out[(size_t)b * 8 + 2 * w] = st;
            }
        }
    }
}

extern "C" void kernel_launch(void* const* d_in, const int* in_sizes, int n_in,
                              void* d_out, int out_size, void* d_ws, size_t ws_size,
                              hipStream_t stream) {
    (void)n_in; (void)out_size; (void)ws_size;
    const float* x = (const float*)d_in[0];
    const float* w = (const float*)d_in[1];
    float* out = (float*)d_out;
    char* ws = (char*)d_ws;
    float* E = (float*)(ws + WS_E_OFF);
    _Float16* Fb = (_Float16*)(ws + WS_FB_OFF);
    const int B = in_sizes[0] / 2;

    hipLaunchKernelGGL(qnn_grid_lds, dim3(NG2), dim3(256), 0, stream, w, E);
    hipLaunchKernelGGL(dft2, dim3(64, 8), dim3(64), 0, stream, E, Fb);
    hipLaunchKernelGGL(contract_mfma, dim3((B + 63) / 64, 1), dim3(256), 0, stream,
                       x, Fb, out, B);
}

// Round 6
// 95.754 us; speedup vs baseline: 1.3092x; 1.0075x over previous
//
#include <hip/hip_runtime.h>
#include <math.h>

#define N_WIRES 8
#define N_LAYERS 6
#define NG 49          // grid per axis (frequencies |n|<=24 -> 49 samples exact)
#define NG2 (NG * NG)  // 2401

// ws layout (bytes):
//   E  : [0, 76832)        8 x 2401 floats (grid EVs, [i][a*49+b])
//   Fb : [76832, +65536)   MFMA-B-fragment-ordered f16 F (pi folded):
//        frag fid=((i*4+ntile)*2+chunk): 64 lanes x 8 f16;
//        lane q*16+n, elem j  =  F_i[k=ntile*16+n][l=chunk*32+q*8+j]
//        (zero for k>=49 or l>=52)
#define WS_E_OFF 0
#define WS_FB_OFF 76832

typedef _Float16 half8 __attribute__((ext_vector_type(8)));
typedef float f32x4 __attribute__((ext_vector_type(4)));

// ---------------------------------------------------------------------------
// DPP-based 16-lane-row sum: quad_perm xor1/xor2 then row_ror 4/8.
// Pure VALU (v_add_f32_dpp). Every lane ends with the full 16-lane sum.
// ---------------------------------------------------------------------------
__device__ __forceinline__ float row16_sum(float v) {
    v += __int_as_float(__builtin_amdgcn_update_dpp(
        0, __float_as_int(v), 0xB1, 0xF, 0xF, true));   // quad_perm [1,0,3,2]
    v += __int_as_float(__builtin_amdgcn_update_dpp(
        0, __float_as_int(v), 0x4E, 0xF, 0xF, true));   // quad_perm [2,3,0,1]
    v += __int_as_float(__builtin_amdgcn_update_dpp(
        0, __float_as_int(v), 0x124, 0xF, 0xF, true));  // row_ror:4
    v += __int_as_float(__builtin_amdgcn_update_dpp(
        0, __float_as_int(v), 0x128, 0xF, 0xF, true));  // row_ror:8
    return v;
}

// ---------------------------------------------------------------------------
// Grid circuit eval, block-per-point (round-5 structure). FROZEN.
// ---------------------------------------------------------------------------
__global__ __launch_bounds__(256) void qnn_grid_lds(const float* __restrict__ w,
                                                    float* __restrict__ E) {
    __shared__ float gates[N_LAYERS * N_WIRES * 8];
    __shared__ float2 bufA[256];
    __shared__ float2 bufB[256];
    __shared__ float partial[4][8];

    const int tid = threadIdx.x;
    const int g = blockIdx.x;
    const int ga = (g * 1338) >> 16;  // g/49, exact for g < 2404
    const int gb = g - ga * NG;
    const float step = (float)(2.0 * M_PI / 49.0);

    if (tid < N_LAYERS * N_WIRES) {
        const int i = tid & 7;
        float wx = w[tid * 3 + 0], wy = w[tid * 3 + 1], wz = w[tid * 3 + 2];
        float sx, cx, sy, cy, sz, cz;
        sincosf(0.5f * wx, &sx, &cx);
        sincosf(0.5f * wy, &sy, &cy);
        sincosf(0.5f * wz, &sz, &cz);
        float A00r = cy * cx, A00i = sy * sx;
        float A01r = -sy * cx, A01i = -cy * sx;
        float A10r = sy * cx, A10i = -cy * sx;
        float A11r = cy * cx, A11i = -sy * sx;
        float U00r = A00r * cz + A00i * sz, U00i = A00i * cz - A00r * sz;
        float U01r = A01r * cz + A01i * sz, U01i = A01i * cz - A01r * sz;
        float U10r = A10r * cz - A10i * sz, U10i = A10i * cz + A10r * sz;
        float U11r = A11r * cz - A11i * sz, U11i = A11i * cz + A11r * sz;
        float V00r, V00i, V01r, V01i, V10r, V10i, V11r, V11i;
        if ((i & 1) == 0) {
            V00r = U01i; V00i = -U01r;
            V01r = U00i; V01i = -U00r;
            V10r = U11i; V10i = -U11r;
            V11r = U10i; V11i = -U10r;
        } else {
            V00r = U01r;  V00i = U01i;
            V01r = -U00r; V01i = -U00i;
            V10r = U11r;  V10i = U11i;
            V11r = -U10r; V11i = -U10i;
        }
        const float xx = (i & 1) ? (step * (float)gb) : (step * (float)ga);
        float se, ce;
        sincosf(0.5f * xx, &se, &ce);
        float* o = gates + tid * 8;
        o[0] = ce * U00r + se * V00r;  o[1] = ce * U00i + se * V00i;
        o[2] = ce * U01r + se * V01r;  o[3] = ce * U01i + se * V01i;
        o[4] = ce * U10r + se * V10r;  o[5] = ce * U10i + se * V10i;
        o[6] = ce * U11r + se * V11r;  o[7] = ce * U11i + se * V11i;
    }

    float ar = (tid == 0) ? 1.0f : 0.0f;
    float ai = 0.0f;
    __syncthreads();

    int flip = 0;
    for (int l = 0; l < N_LAYERS; ++l) {
        #pragma unroll
        for (int i = 0; i < 2; ++i) {
            const float* gm = gates + (l * 8 + i) * 8;
            const int p = 7 - i;
            const int m = 1 << p;
            const int bit = (tid >> p) & 1;
            float2* buf = flip ? bufB : bufA;
            flip ^= 1;
            buf[tid] = make_float2(ar, ai);
            __syncthreads();
            float2 other = buf[tid ^ m];
            float a0r = bit ? other.x : ar, a0i = bit ? other.y : ai;
            float a1r = bit ? ar : other.x, a1i = bit ? ai : other.y;
            float c0r = gm[bit * 4 + 0], c0i = gm[bit * 4 + 1];
            float c1r = gm[bit * 4 + 2], c1i = gm[bit * 4 + 3];
            float nr = c0r * a0r - c0i * a0i + c1r * a1r - c1i * a1i;
            float ni = c0r * a0i + c0i * a0r + c1r * a1i + c1i * a1r;
            ar = nr; ai = ni;
        }
        #pragma unroll
        for (int i = 2; i < 8; ++i) {
            const float* gm = gates + (l * 8 + i) * 8;
            const int p = 7 - i;
            const int m = 1 << p;
            const int bit = (tid >> p) & 1;
            float otr = __shfl_xor(ar, m);
            float oti = __shfl_xor(ai, m);
            float a0r = bit ? otr : ar, a0i = bit ? oti : ai;
            float a1r = bit ? ar : otr, a1i = bit ? ai : oti;
            float c0r = gm[bit * 4 + 0], c0i = gm[bit * 4 + 1];
            float c1r = gm[bit * 4 + 2], c1i = gm[bit * 4 + 3];
            float nr = c0r * a0r - c0i * a0i + c1r * a1r - c1i * a1i;
            float ni = c0r * a0i + c0i * a0r + c1r * a1i + c1i * a1r;
            ar = nr; ai = ni;
        }
        {
            float2* buf = flip ? bufB : bufA;
            flip ^= 1;
            buf[tid] = make_float2(ar, ai);
            __syncthreads();
            float2 src = buf[tid ^ (tid >> 1)];
            ar = src.x; ai = src.y;
        }
    }

    float p = ar * ar + ai * ai;
    float ev[8];
    #pragma unroll
    for (int i = 0; i < 8; ++i) ev[i] = ((tid >> (7 - i)) & 1) ? -p : p;
    #pragma unroll
    for (int i = 0; i < 8; ++i) {
        float v = row16_sum(ev[i]);
        v += __shfl_xor(v, 16);
        v += __shfl_xor(v, 32);
        ev[i] = v;
    }
    const int wave = tid >> 6, lane = tid & 63;
    if (lane == 0) {
        #pragma unroll
        for (int i = 0; i < 8; ++i) partial[wave][i] = ev[i];
    }
    __syncthreads();
    if (tid < 8) {
        E[tid * NG2 + g] = partial[0][tid] + partial[1][tid] + partial[2][tid] + partial[3][tid];
    }
}

// ---------------------------------------------------------------------------
// Fused separable 2D DFT (exact mod-49 table). FROZEN.
// ---------------------------------------------------------------------------
__global__ __launch_bounds__(64) void dft2(const float* __restrict__ E,
                                           _Float16* __restrict__ Fb) {
    const int kp = blockIdx.x, i = blockIdx.y, t = threadIdx.x;
    __shared__ float Es[NG2];
    __shared__ float H[NG];
    __shared__ float tc[NG], ts[NG];
    const float step = (float)(2.0 * M_PI / 49.0);
    const float PI = 3.14159265358979323846f;

    if (t < NG) {
        float s, c;
        sincosf(step * (float)t, &s, &c);
        tc[t] = c; ts[t] = s;
    }
    if (kp < NG) {
        for (int e = t; e < NG2; e += 64) Es[e] = E[i * NG2 + e];
    }
    __syncthreads();

    if (kp < NG && t < NG) {
        const int b = t;
        const int n = (kp + 1) >> 1;  // 0 for kp==0
        const bool use_cos = (kp & 1) || (kp == 0);
        float acc = 0.f;
        int j = 0;
        for (int a = 0; a < NG; ++a) {
            acc = fmaf(Es[a * NG + b], use_cos ? tc[j] : ts[j], acc);
            j += n; if (j >= NG) j -= NG;
        }
        acc *= (kp == 0) ? (1.0f / 49.0f) : (2.0f / 49.0f);
        H[b] = acc;
    }
    __syncthreads();

    const int l = t;
    float acc = 0.f;
    if (kp < NG && l < NG) {
        const int n = (l + 1) >> 1;  // 0 for l==0
        const bool use_cos = (l & 1) || (l == 0);
        int j = 0;
        for (int b = 0; b < NG; ++b) {
            acc = fmaf(H[b], use_cos ? tc[j] : ts[j], acc);
            j += n; if (j >= NG) j -= NG;
        }
        acc *= (l == 0) ? (PI / 49.0f) : (2.0f * PI / 49.0f);
    }
    {
        const int ntile = kp >> 4, n = kp & 15;
        const int chunk = l >> 5, lrem = l & 31;
        const int q = lrem >> 3, j = lrem & 7;
        const int fid = (i * 4 + ntile) * 2 + chunk;
        Fb[fid * 512 + (q * 16 + n) * 8 + j] = (_Float16)acc;
    }
}

// ---------------------------------------------------------------------------
// MFMA contraction, round-6: round-5 structure + occupancy fix. The 8 MFMA
// accumulators were all live before the epilogue (32 VGPR) pushing the
// kernel to ~145 VGPR -> 8 waves/CU (2 blocks). Now MFMA and epilogue-FMA
// are interleaved per nt (2 accs in flight), v0 loaded 4-at-a-time, and
// __launch_bounds__(256,4) enforces <=128 VGPR -> 16 waves/CU.
// Accumulation order per res[ii][r] unchanged (nt ascending) -> bit-identical.
// ---------------------------------------------------------------------------
#define V0PAD 68

__global__ __launch_bounds__(256, 4) void contract_mfma(const float* __restrict__ x,
                                                        const _Float16* __restrict__ Fb,
                                                        float* __restrict__ out, int B) {
    __shared__ float xs0[64], xs1[64];
    __shared__ float v0t[64 * V0PAD];              // 17.4 KB
    __shared__ __align__(16) half8 aS[2 * 4 * 64]; // 8 KB: [c][bg][lane]

    const int tid = threadIdx.x;
    const int bbase = blockIdx.x * 64;
    if (bbase >= B) return;

    const int lane = tid & 63;
    const int w = tid >> 6;
    const int q = lane >> 4;

    // ---- issue this wave's 16 resident B-fragment loads NOW; latency
    //      hides under the build phase below ----
    const half8* FB = (const half8*)Fb;
    half8 bfrag[16];
    #pragma unroll
    for (int f = 0; f < 16; ++f) bfrag[f] = FB[(w * 16 + f) * 64 + lane];

    if (tid < 64) {
        float2 xv = ((const float2*)x)[bbase + tid];
        xs0[tid] = xv.x;
        xs1[tid] = xv.y;
    }
    __syncthreads();

    // ---- v0 table: thread t -> batch b=t&63, k-segment s=t>>6 (16 k's) ----
    {
        const int b = tid & 63, s = tid >> 6;
        const float x0 = xs0[b];
        float c1, s1;
        sincosf(x0, &s1, &c1);
        float s2v = 2.f * s1 * c1, c2v = 1.f - 2.f * s1 * s1;
        float s4v = 2.f * s2v * c2v, c4v = 1.f - 2.f * s2v * s2v;
        float s8v = 2.f * s4v * c4v, c8v = 1.f - 2.f * s4v * s4v;
        float sb, cb;
        if (s == 0) {            // wave-uniform branch (s = tid>>6)
            sb = 0.f; cb = 1.f;
        } else if (s == 1) {
            sb = s8v; cb = c8v;
        } else if (s == 2) {
            sb = 2.f * s8v * c8v; cb = 1.f - 2.f * s8v * s8v;
        } else {
            float s16v = 2.f * s8v * c8v, c16v = 1.f - 2.f * s8v * s8v;
            sb = s16v * c8v + c16v * s8v; cb = c16v * c8v - s16v * s8v;
        }
        float* row = v0t + b * V0PAD + 16 * s;
        const int k0 = 16 * s;
        row[0] = (k0 == 0) ? 1.0f : ((k0 < NG) ? sb : 0.0f);
        float cm = cb, sm = sb;
        #pragma unroll
        for (int j = 1; j < 16; ++j) {
            if (j & 1) {
                float c2 = cm * c1 - sm * s1, s2 = sm * c1 + cm * s1;
                cm = c2; sm = s2;
            }
            float val = (j & 1) ? cm : sm;
            row[j] = ((k0 + j) < NG) ? val : 0.0f;
        }
    }

    // ---- A fragments for THIS thread's batch, staged to LDS ----
    {
        const float x1v = xs1[w * 16 + (lane & 15)];
        float c1, s1;
        sincosf(x1v, &s1, &c1);
        float s2v = 2.f * s1 * c1, c2v = 1.f - 2.f * s1 * s1;
        float s4v = 2.f * s2v * c2v, c4v = 1.f - 2.f * s2v * s2v;
        float s8v = 2.f * s4v * c4v, c8v = 1.f - 2.f * s4v * s4v;
        float s12v = s8v * c4v + c8v * s4v, c12v = c8v * c4v - s8v * s4v;
        float sq = (q == 0) ? 0.f : ((q == 1) ? s4v : ((q == 2) ? s8v : s12v));
        float cq = (q == 0) ? 1.f : ((q == 1) ? c4v : ((q == 2) ? c8v : c12v));
        float s16v = 2.f * s8v * c8v, c16v = 1.f - 2.f * s8v * s8v;
        float sb_c[2], cb_c[2];
        sb_c[0] = sq;                      cb_c[0] = cq;
        sb_c[1] = sq * c16v + cq * s16v;   cb_c[1] = cq * c16v - sq * s16v;
        #pragma unroll
        for (int c = 0; c < 2; ++c) {
            const int l0 = c * 32 + q * 8;
            float cb = cb_c[c], sb = sb_c[c];
            float vals[8];
            vals[0] = (l0 == 0) ? 1.0f : sb;
            float cm = cb, sm = sb;
            #pragma unroll
            for (int j = 1; j < 8; ++j) {
                if (j & 1) {
                    float c2 = cm * c1 - sm * s1, s2 = sm * c1 + cm * s1;
                    cm = c2; sm = s2;
                }
                vals[j] = (j & 1) ? cm : sm;
            }
            half8 af;
            #pragma unroll
            for (int j = 0; j < 8; ++j) {
                af[j] = (_Float16)(((l0 + j) < 52) ? vals[j] : 0.0f);
            }
            aS[(c * 4 + w) * 64 + lane] = af;
        }
    }

    __syncthreads();  // v0t + aS ready; bfrag loads drained by barrier's vmcnt(0)

    // ---- main loop: wave w = i-pair w, iterate batch-groups. NO barriers.
    //      MFMA and epilogue FMA interleaved per nt: only 2 accs live. ----
    #pragma unroll 1
    for (int bg = 0; bg < 4; ++bg) {
        const half8 a0 = aS[(0 * 4 + bg) * 64 + lane];
        const half8 a1 = aS[(1 * 4 + bg) * 64 + lane];

        float res[2][4];
        #pragma unroll
        for (int ii = 0; ii < 2; ++ii)
            #pragma unroll
            for (int r = 0; r < 4; ++r) res[ii][r] = 0.f;

        #pragma unroll
        for (int nt = 0; nt < 4; ++nt) {
            float v0[4];
            #pragma unroll
            for (int r = 0; r < 4; ++r)
                v0[r] = v0t[(bg * 16 + q * 4 + r) * V0PAD + nt * 16 + (lane & 15)];

            f32x4 z = {0.f, 0.f, 0.f, 0.f};
            f32x4 acc0 = __builtin_amdgcn_mfma_f32_16x16x32_f16(a0, bfrag[nt * 2 + 0], z, 0, 0, 0);
            acc0 = __builtin_amdgcn_mfma_f32_16x16x32_f16(a1, bfrag[nt * 2 + 1], acc0, 0, 0, 0);
            f32x4 acc1 = __builtin_amdgcn_mfma_f32_16x16x32_f16(a0, bfrag[(4 + nt) * 2 + 0], z, 0, 0, 0);
            acc1 = __builtin_amdgcn_mfma_f32_16x16x32_f16(a1, bfrag[(4 + nt) * 2 + 1], acc1, 0, 0, 0);

            #pragma unroll
            for (int r = 0; r < 4; ++r) {
                res[0][r] = fmaf(acc0[r], v0[r], res[0][r]);
                res[1][r] = fmaf(acc1[r], v0[r], res[1][r]);
            }
        }

        #pragma unroll
        for (int ii = 0; ii < 2; ++ii)
            #pragma unroll
            for (int r = 0; r < 4; ++r) {
                res[ii][r] = row16_sum(res[ii][r]);  // DPP, no LDS pipe
            }

        if ((lane & 15) == 0) {
            #pragma unroll
            for (int r = 0; r < 4; ++r) {
                const int b = bbase + bg * 16 + q * 4 + r;
                float2 st = make_float2(res[0][r], res[1][r]);
                *(float2*)&out[(size_t)b * 8 + 2 * w] = st;
            }
        }
    }
}

extern "C" void kernel_launch(void* const* d_in, const int* in_sizes, int n_in,
                              void* d_out, int out_size, void* d_ws, size_t ws_size,
                              hipStream_t stream) {
    (void)n_in; (void)out_size; (void)ws_size;
    const float* x = (const float*)d_in[0];
    const float* w = (const float*)d_in[1];
    float* out = (float*)d_out;
    char* ws = (char*)d_ws;
    float* E = (float*)(ws + WS_E_OFF);
    _Float16* Fb = (_Float16*)(ws + WS_FB_OFF);
    const int B = in_sizes[0] / 2;

    hipLaunchKernelGGL(qnn_grid_lds, dim3(NG2), dim3(256), 0, stream, w, E);
    hipLaunchKernelGGL(dft2, dim3(64, 8), dim3(64), 0, stream, E, Fb);
    hipLaunchKernelGGL(contract_mfma, dim3((B + 63) / 64, 1), dim3(256), 0, stream,
                       x, Fb, out, B);
}